// Round 1
// baseline (254.545 us; speedup 1.0000x reference)
//
#include <hip/hip_runtime.h>
#include <math.h>

// Problem constants (B=4, T=4096, D=2048, K=4 from the reference setup)
#define D_DIM 2048
#define T_DIM 4096
#define K_DIM 4
#define TT 32   // time-steps per block in conv kernel

// ---------------- Kernel 1: per-row inverse RMS ----------------
// One wave (64 lanes) per (b,t) row of 2048 floats. 8 float4 loads/lane,
// shuffle reduce, lane 0 writes inv_rms.
__global__ __launch_bounds__(256) void rms_kernel(const float* __restrict__ x,
                                                  float* __restrict__ inv_rms) {
    const int wave = blockIdx.x * 4 + (threadIdx.x >> 6);
    const int lane = threadIdx.x & 63;
    const float4* xr = (const float4*)(x + (size_t)wave * D_DIM);
    float s = 0.f;
#pragma unroll
    for (int i = 0; i < (D_DIM / 4) / 64; ++i) {   // 8 iterations
        float4 v = xr[lane + i * 64];
        s += v.x * v.x + v.y * v.y + v.z * v.z + v.w * v.w;
    }
#pragma unroll
    for (int off = 32; off > 0; off >>= 1) s += __shfl_down(s, off, 64);
    if (lane == 0) inv_rms[wave] = rsqrtf(s * (1.0f / D_DIM) + 1e-5f);
}

// ---------------- Kernel 2: fused norm-scale + causal conv + SiLU ----------------
// Grid: (D/1024, T/TT, B). Block: 256 threads, each owns 4 contiguous d.
// Sliding 4-deep window over t kept in registers; x read once (+3 halo rows).
__global__ __launch_bounds__(256) void conv_kernel(const float* __restrict__ x,
                                                   const float* __restrict__ g,
                                                   const float* __restrict__ w,
                                                   const float* __restrict__ inv_rms,
                                                   float* __restrict__ out) {
    const int b  = blockIdx.z;
    const int t0 = blockIdx.y * TT;
    const int d0 = blockIdx.x * 1024 + threadIdx.x * 4;

    __shared__ float s_r[TT + 3];
    if (threadIdx.x < TT + 3) {
        const int t = t0 - 3 + (int)threadIdx.x;
        s_r[threadIdx.x] = (t >= 0) ? inv_rms[(size_t)b * T_DIM + t] : 0.f;
    }
    __syncthreads();

    const float4 gv = *(const float4*)(g + d0);
    float wgt[4][4];   // wgt[j][k]: weight k for my j-th channel
#pragma unroll
    for (int j = 0; j < 4; ++j) {
        float4 wv = *(const float4*)(w + (size_t)(d0 + j) * K_DIM);
        wgt[j][0] = wv.x; wgt[j][1] = wv.y; wgt[j][2] = wv.z; wgt[j][3] = wv.w;
    }

    const float* xb = x   + ((size_t)b * T_DIM) * D_DIM + d0;
    float*       ob = out + ((size_t)b * T_DIM) * D_DIM + d0;

    // window: win[0]=y[t-3], win[1]=y[t-2], win[2]=y[t-1]
    float win[3][4];
#pragma unroll
    for (int p = 0; p < 3; ++p) {
        const int t = t0 - 3 + p;
        if (t >= 0) {
            float4 xv = *(const float4*)(xb + (size_t)t * D_DIM);
            const float r = s_r[p];
            win[p][0] = xv.x * r * gv.x;
            win[p][1] = xv.y * r * gv.y;
            win[p][2] = xv.z * r * gv.z;
            win[p][3] = xv.w * r * gv.w;
        } else {
            win[p][0] = win[p][1] = win[p][2] = win[p][3] = 0.f;
        }
    }

#pragma unroll
    for (int i = 0; i < TT; ++i) {
        const int t = t0 + i;
        float4 xv = *(const float4*)(xb + (size_t)t * D_DIM);
        const float r = s_r[i + 3];
        float yn[4] = { xv.x * r * gv.x, xv.y * r * gv.y,
                        xv.z * r * gv.z, xv.w * r * gv.w };
        float4 o;
        float* op = &o.x;
#pragma unroll
        for (int j = 0; j < 4; ++j) {
            const float v = wgt[j][0] * win[0][j] + wgt[j][1] * win[1][j] +
                            wgt[j][2] * win[2][j] + wgt[j][3] * yn[j];
            op[j] = v / (1.f + __expf(-v));   // SiLU
        }
        *(float4*)(ob + (size_t)t * D_DIM) = o;
#pragma unroll
        for (int j = 0; j < 4; ++j) {
            win[0][j] = win[1][j];
            win[1][j] = win[2][j];
            win[2][j] = yn[j];
        }
    }
}

extern "C" void kernel_launch(void* const* d_in, const int* in_sizes, int n_in,
                              void* d_out, int out_size, void* d_ws, size_t ws_size,
                              hipStream_t stream) {
    const float* x = (const float*)d_in[0];
    const float* g = (const float*)d_in[1];   // norm_weight [D]
    const float* w = (const float*)d_in[2];   // conv_weight [D,1,K]
    float* out = (float*)d_out;

    const int total = in_sizes[0];            // B*T*D
    const int rows  = total / D_DIM;          // B*T
    const int B     = rows / T_DIM;

    float* inv_rms = (float*)d_ws;            // rows floats (64 KiB)

    rms_kernel<<<rows / 4, 256, 0, stream>>>(x, inv_rms);

    dim3 grid(D_DIM / 1024, T_DIM / TT, B);
    conv_kernel<<<grid, 256, 0, stream>>>(x, g, w, inv_rms, out);
}

// Round 2
// 241.087 us; speedup vs baseline: 1.0558x; 1.0558x over previous
//
#include <hip/hip_runtime.h>
#include <math.h>

// Problem constants (B=4, T=4096, D=2048, K=4 from the reference setup)
#define D_DIM 2048
#define T_DIM 4096
#define K_DIM 4
#define TT    16               // time-steps (outputs) per block
#define NROW  (TT + 3)         // rows loaded incl. 3-row causal halo = 19
#define NTHREADS (D_DIM / 4)   // 512: one block spans the full D row, float4/thread
#define NWAVES  (NTHREADS / 64)

// One fused kernel: RMSNorm (block-wide reduction over D) + causal depthwise
// conv (K=4, sliding in registers) + SiLU. x is read exactly once (+3/16 halo).
__global__ __launch_bounds__(NTHREADS) void fused_kernel(
    const float* __restrict__ x,
    const float* __restrict__ g,
    const float* __restrict__ w,
    float* __restrict__ out)
{
    const int b    = blockIdx.y;
    const int t0   = blockIdx.x * TT;
    const int tid  = threadIdx.x;
    const int d0   = tid * 4;
    const int lane = tid & 63;
    const int wid  = tid >> 6;

    __shared__ float s_part[NROW][NWAVES];
    __shared__ float s_inv[NROW];

    const float* xb = x + ((size_t)b * T_DIM) * D_DIM + d0;

    // ---- Phase A: load all 19 rows up front (max MLP), row sums of squares ----
    float4 xv[NROW];
#pragma unroll
    for (int r = 0; r < NROW; ++r) {
        const int t = t0 - 3 + r;
        if (t >= 0) {
            xv[r] = *(const float4*)(xb + (size_t)t * D_DIM);
        } else {
            xv[r] = make_float4(0.f, 0.f, 0.f, 0.f);
        }
    }
#pragma unroll
    for (int r = 0; r < NROW; ++r) {
        float p = xv[r].x * xv[r].x + xv[r].y * xv[r].y +
                  xv[r].z * xv[r].z + xv[r].w * xv[r].w;
#pragma unroll
        for (int off = 32; off > 0; off >>= 1) p += __shfl_down(p, off, 64);
        if (lane == 0) s_part[r][wid] = p;
    }
    __syncthreads();
    if (tid < NROW) {
        float s = 0.f;
#pragma unroll
        for (int wv = 0; wv < NWAVES; ++wv) s += s_part[tid][wv];
        s_inv[tid] = rsqrtf(s * (1.0f / D_DIM) + 1e-5f);
    }
    __syncthreads();

    // ---- Normalize rows in place: y = x * inv_rms * g ----
    const float4 gv = *(const float4*)(g + d0);
#pragma unroll
    for (int r = 0; r < NROW; ++r) {
        const float rv = s_inv[r];
        xv[r].x *= rv * gv.x;
        xv[r].y *= rv * gv.y;
        xv[r].z *= rv * gv.z;
        xv[r].w *= rv * gv.w;
    }

    // ---- Per-channel conv weights (w is [D,1,4], contiguous float4/channel) ----
    float wgt[4][4];
#pragma unroll
    for (int j = 0; j < 4; ++j) {
        float4 wv = *(const float4*)(w + (size_t)(d0 + j) * K_DIM);
        wgt[j][0] = wv.x; wgt[j][1] = wv.y; wgt[j][2] = wv.z; wgt[j][3] = wv.w;
    }

    // ---- Causal conv + SiLU, all in registers; store ----
    float* ob = out + ((size_t)b * T_DIM) * D_DIM + d0;
#pragma unroll
    for (int i = 0; i < TT; ++i) {
        float4 o;
        float* op = &o.x;
#pragma unroll
        for (int j = 0; j < 4; ++j) {
            const float v = wgt[j][0] * ((const float*)&xv[i    ])[j]
                          + wgt[j][1] * ((const float*)&xv[i + 1])[j]
                          + wgt[j][2] * ((const float*)&xv[i + 2])[j]
                          + wgt[j][3] * ((const float*)&xv[i + 3])[j];
            // SiLU: v * sigmoid(v); raw v_rcp_f32 is plenty accurate here
            op[j] = v * __builtin_amdgcn_rcpf(1.f + __expf(-v));
        }
        *(float4*)(ob + (size_t)(t0 + i) * D_DIM) = o;
    }
}

extern "C" void kernel_launch(void* const* d_in, const int* in_sizes, int n_in,
                              void* d_out, int out_size, void* d_ws, size_t ws_size,
                              hipStream_t stream) {
    const float* x = (const float*)d_in[0];
    const float* g = (const float*)d_in[1];   // norm_weight [D]
    const float* w = (const float*)d_in[2];   // conv_weight [D,1,K]
    float* out = (float*)d_out;

    const int total = in_sizes[0];            // B*T*D
    const int rows  = total / D_DIM;          // B*T
    const int B     = rows / T_DIM;

    dim3 grid(T_DIM / TT, B);
    fused_kernel<<<grid, NTHREADS, 0, stream>>>(x, g, w, out);
}

// Round 4
// 239.160 us; speedup vs baseline: 1.0643x; 1.0081x over previous
//
#include <hip/hip_runtime.h>
#include <math.h>

// Problem constants (B=4, T=4096, D=2048, K=4)
#define D_DIM 2048
#define T_DIM 4096
#define TT    16               // output rows per block
#define NT    (D_DIM / 4)      // 512 threads: block spans full D, float4/thread
#define NW    (NT / 64)        // 8 waves

typedef float vfloat4 __attribute__((ext_vector_type(4)));  // native vec for nontemporal builtin

// intra-wave sum of squares of a float4, reduced across 64 lanes
__device__ __forceinline__ float row_partial(float4 v) {
    float p = v.x * v.x + v.y * v.y + v.z * v.z + v.w * v.w;
#pragma unroll
    for (int off = 32; off > 0; off >>= 1) p += __shfl_down(p, off, 64);
    return p;
}

// sum 8 wave-partials (two broadcast float4 LDS reads) -> inverse RMS
__device__ __forceinline__ float inv_from(const float* sp) {
    float4 a = *(const float4*)sp;
    float4 b = *(const float4*)(sp + 4);
    float s = a.x + a.y + a.z + a.w + b.x + b.y + b.z + b.w;
    return rsqrtf(s * (1.0f / D_DIM) + 1e-5f);
}

__device__ __forceinline__ float silu(float v) {
    return v * __builtin_amdgcn_rcpf(1.f + __expf(-v));
}

__device__ __forceinline__ void nt_store4(float* p, float a, float b, float c, float d) {
    vfloat4 v = { a, b, c, d };
    __builtin_nontemporal_store(v, (vfloat4*)p);
}

// Fused streaming kernel: per-row RMSNorm (block reduction) + causal depthwise
// conv K=4 (register sliding window) + SiLU. x read once (+3/16 halo).
__global__ __launch_bounds__(NT, 4) void fused_kernel(
    const float* __restrict__ x,
    const float* __restrict__ g,
    const float* __restrict__ w,
    float* __restrict__ out)
{
    const int b    = blockIdx.y;
    const int t0   = blockIdx.x * TT;
    const int tid  = threadIdx.x;
    const int d0   = tid * 4;
    const int lane = tid & 63;
    const int wid  = tid >> 6;

    __shared__ __align__(16) float hpart[3][NW];
    __shared__ __align__(16) float part[2][2][NW];   // [iter parity][row in pair][wave]

    const float* xb = x   + (size_t)b * T_DIM * D_DIM + d0;
    float*       ob = out + (size_t)b * T_DIM * D_DIM + d0;

    // ---- halo rows t0-3 .. t0-1 ----
    float4 hv[3];
#pragma unroll
    for (int r = 0; r < 3; ++r) {
        const int t = t0 - 3 + r;
        hv[r] = (t >= 0) ? *(const float4*)(xb + (size_t)t * D_DIM)
                         : make_float4(0.f, 0.f, 0.f, 0.f);
    }
    // ---- prefetch first 4 main rows ----
    float4 cur0 = *(const float4*)(xb + (size_t)(t0 + 0) * D_DIM);
    float4 cur1 = *(const float4*)(xb + (size_t)(t0 + 1) * D_DIM);
    float4 nxt0 = *(const float4*)(xb + (size_t)(t0 + 2) * D_DIM);
    float4 nxt1 = *(const float4*)(xb + (size_t)(t0 + 3) * D_DIM);

    const float4 gv = *(const float4*)(g + d0);
    float wgt[4][4];
#pragma unroll
    for (int j = 0; j < 4; ++j) {
        float4 wv = *(const float4*)(w + (size_t)(d0 + j) * 4);
        wgt[j][0] = wv.x; wgt[j][1] = wv.y; wgt[j][2] = wv.z; wgt[j][3] = wv.w;
    }

    // ---- halo RMS + normalize into sliding window ----
#pragma unroll
    for (int r = 0; r < 3; ++r) {
        float p = row_partial(hv[r]);
        if (lane == 0) hpart[r][wid] = p;
    }
    __syncthreads();

    float win[3][4];
#pragma unroll
    for (int r = 0; r < 3; ++r) {
        const float inv = inv_from(hpart[r]);
        win[r][0] = hv[r].x * inv * gv.x;
        win[r][1] = hv[r].y * inv * gv.y;
        win[r][2] = hv[r].z * inv * gv.z;
        win[r][3] = hv[r].w * inv * gv.w;
    }

    // ---- main loop: 2 rows per iteration, 1 barrier per pair ----
#pragma unroll
    for (int i = 0; i < TT; i += 2) {
        const int slot = (i >> 1) & 1;
        float p0 = row_partial(cur0);
        float p1 = row_partial(cur1);
        if (lane == 0) { part[slot][0][wid] = p0; part[slot][1][wid] = p1; }
        __syncthreads();

        // issue prefetch for pair i+4 while the partial sums are consumed
        float4 f0, f1;
        if (i + 4 < TT) {
            f0 = *(const float4*)(xb + (size_t)(t0 + i + 4) * D_DIM);
            f1 = *(const float4*)(xb + (size_t)(t0 + i + 5) * D_DIM);
        } else {
            f0 = make_float4(0.f, 0.f, 0.f, 0.f);
            f1 = f0;
        }

        const float r0 = inv_from(part[slot][0]);
        const float r1 = inv_from(part[slot][1]);
        const float y0[4] = { cur0.x * r0 * gv.x, cur0.y * r0 * gv.y,
                              cur0.z * r0 * gv.z, cur0.w * r0 * gv.w };
        const float y1[4] = { cur1.x * r1 * gv.x, cur1.y * r1 * gv.y,
                              cur1.z * r1 * gv.z, cur1.w * r1 * gv.w };

        float o0[4], o1[4];
#pragma unroll
        for (int j = 0; j < 4; ++j) {
            const float v0 = wgt[j][0] * win[0][j] + wgt[j][1] * win[1][j] +
                             wgt[j][2] * win[2][j] + wgt[j][3] * y0[j];
            o0[j] = silu(v0);
            const float v1 = wgt[j][0] * win[1][j] + wgt[j][1] * win[2][j] +
                             wgt[j][2] * y0[j]     + wgt[j][3] * y1[j];
            o1[j] = silu(v1);
        }
        nt_store4(ob + (size_t)(t0 + i)     * D_DIM, o0[0], o0[1], o0[2], o0[3]);
        nt_store4(ob + (size_t)(t0 + i + 1) * D_DIM, o1[0], o1[1], o1[2], o1[3]);

        // slide window by 2 rows
#pragma unroll
        for (int j = 0; j < 4; ++j) {
            win[0][j] = win[2][j];
            win[1][j] = y0[j];
            win[2][j] = y1[j];
        }
        cur0 = nxt0; cur1 = nxt1; nxt0 = f0; nxt1 = f1;
    }
}

extern "C" void kernel_launch(void* const* d_in, const int* in_sizes, int n_in,
                              void* d_out, int out_size, void* d_ws, size_t ws_size,
                              hipStream_t stream) {
    const float* x = (const float*)d_in[0];
    const float* g = (const float*)d_in[1];   // norm_weight [D]
    const float* w = (const float*)d_in[2];   // conv_weight [D,1,K]
    float* out = (float*)d_out;

    const int total = in_sizes[0];            // B*T*D
    const int rows  = total / D_DIM;          // B*T
    const int B     = rows / T_DIM;

    dim3 grid(T_DIM / TT, B);
    fused_kernel<<<grid, NT, 0, stream>>>(x, g, w, out);
}